// Round 1
// baseline (1322.505 us; speedup 1.0000x reference)
//
#include <hip/hip_runtime.h>

// NeuralNetwork_6519760355912 — MI355X (gfx950)
//
// out = ((relu((x@W1)/2048 + mean_i b1)) @ W2)/1024 + mean_i b2
//
// Fusion: mean_i(b) and (v@W)/D share the same sum over i:
//   h[b][j]   = relu( (1/2048) * sum_i ( x[b][i]*W1[i][j] + b1[b][i][j] ) )
//   out[b][j] =        (1/1024) * sum_i ( h[b][i]*W2[i][j] + b2[b][i][j] )
// so the tiny GEMMs ride along the HBM-bound stream over b1 (839 MB) and
// b2 (410 MB). HBM floor ~1.26 GB => ~200 us at 6.3 TB/s.

namespace {
constexpr int B_   = 100;
constexpr int DIN  = 2048;
constexpr int DH   = 1024;
constexpr int DOUT = 1000;

constexpr int CH1    = 16;          // i-chunks per batch row, layer 1
constexpr int CHUNK1 = DIN / CH1;   // 128
constexpr int CH2    = 16;          // i-chunks per batch row, layer 2
constexpr int CHUNK2 = DH / CH2;    // 64
} // namespace

// Layer 1 partial: acc1[b][j] += sum_{i in chunk} (x[b][i]*W1[i][j] + b1[b][i][j])
// Block = (b, chunk). 256 threads cover j as float4 (DH/4 = 256). Each i reads a
// contiguous 4 KB row of b1 -> perfectly coalesced HBM stream; W1 row from L2/L3.
__global__ __launch_bounds__(256)
void l1_partial(const float* __restrict__ x, const float* __restrict__ W1,
                const float* __restrict__ b1, float* __restrict__ acc1)
{
    const int blk = blockIdx.x;
    const int b   = blk / CH1;
    const int ch  = blk - b * CH1;
    const int i0  = ch * CHUNK1;
    const int t   = threadIdx.x;            // j4 = t, j = 4t..4t+3

    __shared__ float xs[CHUNK1];
    if (t < CHUNK1) xs[t] = x[b * DIN + i0 + t];
    __syncthreads();

    const float4* __restrict__ b1v = reinterpret_cast<const float4*>(b1);
    const float4* __restrict__ w1v = reinterpret_cast<const float4*>(W1);

    float4 acc = make_float4(0.f, 0.f, 0.f, 0.f);
    size_t b1base = ((size_t)b * DIN + i0) * (DH / 4) + t;
    size_t w1base = (size_t)i0 * (DH / 4) + t;
    #pragma unroll 4
    for (int k = 0; k < CHUNK1; ++k) {
        float4 bv = b1v[b1base + (size_t)k * (DH / 4)];
        float4 wv = w1v[w1base + (size_t)k * (DH / 4)];
        const float xv = xs[k];
        acc.x += bv.x + xv * wv.x;
        acc.y += bv.y + xv * wv.y;
        acc.z += bv.z + xv * wv.z;
        acc.w += bv.w + xv * wv.w;
    }
    float* dst = acc1 + (size_t)b * DH + 4 * t;
    atomicAdd(dst + 0, acc.x);
    atomicAdd(dst + 1, acc.y);
    atomicAdd(dst + 2, acc.z);
    atomicAdd(dst + 3, acc.w);
}

// h = relu(acc1 / 2048)
__global__ __launch_bounds__(256)
void l1_finalize(const float* __restrict__ acc1, float* __restrict__ h)
{
    const int idx = blockIdx.x * 256 + threadIdx.x;
    if (idx < B_ * DH) h[idx] = fmaxf(acc1[idx] * (1.0f / (float)DIN), 0.0f);
}

// Layer 2 partial: out[b][j] += (1/1024) * sum_{i in chunk} (h[b][i]*W2[i][j] + b2[b][i][j])
// DOUT=1000 -> 250 float4 lanes active (row stride 4000 B is 16B-aligned).
__global__ __launch_bounds__(256)
void l2_partial(const float* __restrict__ h, const float* __restrict__ W2,
                const float* __restrict__ b2, float* __restrict__ out)
{
    const int blk = blockIdx.x;
    const int b   = blk / CH2;
    const int ch  = blk - b * CH2;
    const int i0  = ch * CHUNK2;
    const int t   = threadIdx.x;

    __shared__ float hs[CHUNK2];
    if (t < CHUNK2) hs[t] = h[b * DH + i0 + t];
    __syncthreads();

    if (t < DOUT / 4) {                      // 250 active lanes
        const float4* __restrict__ b2v = reinterpret_cast<const float4*>(b2);
        const float4* __restrict__ w2v = reinterpret_cast<const float4*>(W2);
        float4 acc = make_float4(0.f, 0.f, 0.f, 0.f);
        size_t b2base = ((size_t)b * DH + i0) * (DOUT / 4) + t;
        size_t w2base = (size_t)i0 * (DOUT / 4) + t;
        #pragma unroll 4
        for (int k = 0; k < CHUNK2; ++k) {
            float4 bv = b2v[b2base + (size_t)k * (DOUT / 4)];
            float4 wv = w2v[w2base + (size_t)k * (DOUT / 4)];
            const float hv = hs[k];
            acc.x += bv.x + hv * wv.x;
            acc.y += bv.y + hv * wv.y;
            acc.z += bv.z + hv * wv.z;
            acc.w += bv.w + hv * wv.w;
        }
        float* dst = out + (size_t)b * DOUT + 4 * t;
        const float s = 1.0f / (float)DH;
        atomicAdd(dst + 0, acc.x * s);
        atomicAdd(dst + 1, acc.y * s);
        atomicAdd(dst + 2, acc.z * s);
        atomicAdd(dst + 3, acc.w * s);
    }
}

extern "C" void kernel_launch(void* const* d_in, const int* in_sizes, int n_in,
                              void* d_out, int out_size, void* d_ws, size_t ws_size,
                              hipStream_t stream)
{
    const float* x  = (const float*)d_in[0];
    const float* W1 = (const float*)d_in[1];
    const float* b1 = (const float*)d_in[2];
    const float* W2 = (const float*)d_in[3];
    const float* b2 = (const float*)d_in[4];
    float* out = (float*)d_out;

    float* acc1 = (float*)d_ws;                   // B*DH f32 = 400 KB
    float* h    = acc1 + (size_t)B_ * DH;         // B*DH f32 = 400 KB

    // ws/out are re-poisoned to 0xAA before every timed launch; zero what we
    // accumulate into. hipMemsetAsync on the stream is graph-capture safe.
    hipMemsetAsync(acc1,  0, (size_t)B_ * DH   * sizeof(float), stream);
    hipMemsetAsync(d_out, 0, (size_t)B_ * DOUT * sizeof(float), stream);

    l1_partial<<<B_ * CH1, 256, 0, stream>>>(x, W1, b1, acc1);
    l1_finalize<<<(B_ * DH + 255) / 256, 256, 0, stream>>>(acc1, h);
    l2_partial<<<B_ * CH2, 256, 0, stream>>>(h, W2, b2, out);
}